// Round 1
// 403.042 us; speedup vs baseline: 1.0076x; 1.0076x over previous
//
#include <hip/hip_runtime.h>
#include <math.h>

// Attention_10230612099272: B=2,S=2048,H=2048,nh=16,hd=128, fp32 in/out,
// bf16 MFMA internally.
// R7: gemm_qkv rewritten as the 256x256 8-phase counted-vmcnt template
// (T2 swizzle + T3/T4 8-phase + T5 setprio, m201 structure): 512 thr,
// 8 waves (2Mx4N, 128x64 each), BK=64, 128KB LDS 2-deep double buffer,
// global_load_lds with inverse-swizzled global sources, one 16KB half-tile
// staged per phase, vmcnt(6) once per K-tile (never 0 in steady state),
// raw s_barrier (no compiler vmcnt(0) drain). gemm_out / attn unchanged.

typedef __bf16 bf16;
typedef __attribute__((ext_vector_type(8))) __bf16 bf16x8;
typedef __attribute__((ext_vector_type(4))) __bf16 bf16x4;
typedef __attribute__((ext_vector_type(4))) float f32x4;

#define S_LEN 2048
#define NHEAD 16
#define HD 128

__device__ __forceinline__ f32x4 mfma16(bf16x8 a, bf16x8 b, f32x4 c) {
    return __builtin_amdgcn_mfma_f32_16x16x32_bf16(a, b, c, 0, 0, 0);
}

__device__ __forceinline__ void gload16(const bf16* g, bf16* s) {
    __builtin_amdgcn_global_load_lds(
        (const __attribute__((address_space(1))) void*)g,
        (__attribute__((address_space(3))) void*)s, 16, 0, 0);
}

// raw barrier: no implicit vmcnt/lgkmcnt drain; empty asm = compiler fence
#define BAR()                                  \
    do {                                       \
        asm volatile("" ::: "memory");         \
        __builtin_amdgcn_s_barrier();          \
        asm volatile("" ::: "memory");         \
    } while (0)
#define WAITV(n) asm volatile("s_waitcnt vmcnt(" #n ")" ::: "memory")
#define SCHED0() __builtin_amdgcn_sched_barrier(0)

// ---------------- fp32 -> bf16 elementwise ----------------
__global__ __launch_bounds__(256) void cvt_f32_bf16(const float* __restrict__ x,
                                                    bf16* __restrict__ y, int n) {
    int i = (blockIdx.x * 256 + threadIdx.x) * 4;
    if (i + 3 < n) {
        const float4 v = *(const float4*)(x + i);
        bf16x4 o;
        o[0] = (bf16)v.x; o[1] = (bf16)v.y; o[2] = (bf16)v.z; o[3] = (bf16)v.w;
        *(bf16x4*)(y + i) = o;
    }
}

// ---------------- RoPE sin/cos tables: [s][d], 2048x128 fp32 ----------
__global__ __launch_bounds__(128) void rope_tables(float* __restrict__ st,
                                                   float* __restrict__ ct) {
    const int s = blockIdx.x, d = threadIdx.x;
    const float invf = exp2f(-0.20762050593046013f * (float)(d >> 1));
    float sn, cs;
    sincosf((float)s * invf, &sn, &cs);
    st[(s << 7) | d] = sn;
    ct[(s << 7) | d] = cs;
}

// ---------------- W (k,n) fp32 -> Wt (n,k) bf16 ----------------
__global__ __launch_bounds__(256) void transpose_cvt(const float* __restrict__ W,
                                                     bf16* __restrict__ Wt,
                                                     int Kd, int Nd) {
    __shared__ float tile[32][33];
    const int tx = threadIdx.x & 31, ty = threadIdx.x >> 5;
    const int bn = blockIdx.x * 32, bk = blockIdx.y * 32;
#pragma unroll
    for (int r = 0; r < 32; r += 8)
        tile[ty + r][tx] = W[(size_t)(bk + ty + r) * Nd + bn + tx];
    __syncthreads();
#pragma unroll
    for (int r = 0; r < 32; r += 8)
        Wt[(size_t)(bn + ty + r) * Kd + bk + tx] = (bf16)tile[tx][ty + r];
}

// ------------- fused QKV GEMM: C[4096, 6144] = X . Wt3^T -------------
// 256x256 tile, BK=64, 8 waves (2Mx4N, 128x64 per wave), 4 phases/K-tile:
//   P1: read A-mh0(8)+B-nh0(4); stage B(t+1)r1; MFMA (mh0,nh0)
//   P2: read B-nh1(4);          stage A(t+2)r0; MFMA (mh0,nh1)
//   P3: read A-mh1(8);          stage B(t+2)r0; MFMA (mh1,nh1)
//   P4: (reg reuse);            stage A(t+2)r1; MFMA (mh1,nh0); vmcnt(6)
// LDS regions (16KB units): A r0 = tile rows {0-63,128-191} (the mh0 rows
// of both wr groups), A r1 = {64-127,192-255}; B r0 = n rows
// {0-31,64-95,128-159,192-223}, r1 = the rest. Each staged unit targets a
// region whose last reader finished one phase earlier. XOR chunk swizzle
// (cc ^= row&7) applied via inverse-swizzled GLOBAL source + swizzled read.
// n-segment 0: Q (bias+RoPE, *1/sqrt(hd) -> [b,h,s,d]); 1: K (bias+RoPE);
// 2: V (bias -> Vt [b,h,d,s] via per-wave LDS transpose).
#define STG_A(kt, reg)                                                        \
    do {                                                                      \
        bf16* d_ = smem + (((((kt) & 1) << 1) + (reg)) << 13);                \
        const size_t ko_ = (size_t)((kt) << 6) + ((size_t)(reg) << 17);       \
        gload16(A + aoff0 + ko_, d_ + loff0);                                 \
        gload16(A + aoff1 + ko_, d_ + loff1);                                 \
    } while (0)
#define STG_B(kt, reg)                                                        \
    do {                                                                      \
        bf16* d_ = smem + 32768 + (((((kt) & 1) << 1) + (reg)) << 13);        \
        const size_t ko_ = (size_t)((kt) << 6) + ((size_t)(reg) << 16);       \
        gload16(Bt + boff0 + ko_, d_ + loff0);                                \
        gload16(Bt + boff1 + ko_, d_ + loff1);                                \
    } while (0)

__global__ __launch_bounds__(512, 2)
void gemm_qkv(const bf16* __restrict__ A, const bf16* __restrict__ Bt,
              const float* __restrict__ bq, const float* __restrict__ bk,
              const float* __restrict__ bv, bf16* __restrict__ Qo,
              bf16* __restrict__ Ko, bf16* __restrict__ Vo,
              const float* __restrict__ stab, const float* __restrict__ ctab) {
    __shared__ __align__(16) bf16 smem[65536];  // 128KB: A[2][2][8192] | B[2][2][8192]
    const int tid = threadIdx.x;
    const int w = tid >> 6, l = tid & 63;
    const int lr = l & 15, lq = l >> 4;
    const int wr = w >> 2, wc = w & 3;  // 2M x 4N wave grid
    const int m0 = blockIdx.y * 256, n0 = blockIdx.x * 256;

    // per-thread staging offsets (chunk = c*512+tid; 16B each; src carries
    // the inverse XOR swizzle so linear LDS + swizzled read is consistent)
    size_t aoff0, aoff1, boff0, boff1;
    {
        const int ch0 = tid, ch1 = 512 + tid;
        const int rl0 = ch0 >> 3, rl1 = ch1 >> 3;
        const int cc0 = (ch0 & 7) ^ (rl0 & 7), cc1 = (ch1 & 7) ^ (rl1 & 7);
        aoff0 = (size_t)(m0 + (rl0 & 63) + ((rl0 >> 6) << 7)) * 2048 + (cc0 << 3);
        aoff1 = (size_t)(m0 + (rl1 & 63) + ((rl1 >> 6) << 7)) * 2048 + (cc1 << 3);
        boff0 = (size_t)(n0 + (rl0 & 31) + ((rl0 >> 5) << 6)) * 2048 + (cc0 << 3);
        boff1 = (size_t)(n0 + (rl1 & 31) + ((rl1 >> 5) << 6)) * 2048 + (cc1 << 3);
    }
    const int loff0 = tid << 3, loff1 = 4096 + (tid << 3);

    f32x4 acc[8][4];
    const f32x4 fz = {0.f, 0.f, 0.f, 0.f};
#pragma unroll
    for (int i = 0; i < 8; ++i)
#pragma unroll
        for (int j = 0; j < 4; ++j) acc[i][j] = fz;

    // prologue: tile0 fully + 3 units of tile1; drain tile0 (vmcnt(6))
    STG_A(0, 0); STG_B(0, 0); STG_B(0, 1); STG_A(0, 1);
    STG_A(1, 0); STG_B(1, 0); STG_A(1, 1);
    WAITV(6);
    BAR();

    const int csel0 = ((0 * 4 + lq) ^ (lr & 7)) << 3;  // k-chunk byte sel, s=0
    const int csel1 = ((1 * 4 + lq) ^ (lr & 7)) << 3;  // s=1
    const int arow = (wr * 64 + lr) << 6;              // + i*1024
    const int brow = (wc * 32 + lr) << 6;              // + j*1024

#pragma unroll 2
    for (int t = 0; t < 32; ++t) {
        const int buf = t & 1;
        const int abase = (buf << 1) << 13;
        const int bbase = 32768 + ((buf << 1) << 13);
        bf16x8 a[4][2], b0[2][2], b1[2][2];

        // ---------------- P1: A-mh0 + B-nh0 ----------------
#pragma unroll
        for (int i = 0; i < 4; ++i) {
            a[i][0] = *(const bf16x8*)&smem[abase + arow + (i << 10) + csel0];
            a[i][1] = *(const bf16x8*)&smem[abase + arow + (i << 10) + csel1];
        }
#pragma unroll
        for (int j = 0; j < 2; ++j) {
            b0[j][0] = *(const bf16x8*)&smem[bbase + brow + (j << 10) + csel0];
            b0[j][1] = *(const bf16x8*)&smem[bbase + brow + (j << 10) + csel1];
        }
        if (t + 1 < 32) STG_B(t + 1, 1);
        BAR();
        SCHED0();
        __builtin_amdgcn_s_setprio(1);
#pragma unroll
        for (int i = 0; i < 4; ++i)
#pragma unroll
            for (int j = 0; j < 2; ++j) {
                acc[i][j] = mfma16(a[i][0], b0[j][0], acc[i][j]);
                acc[i][j] = mfma16(a[i][1], b0[j][1], acc[i][j]);
            }
        __builtin_amdgcn_s_setprio(0);
        SCHED0();
        BAR();

        // ---------------- P2: B-nh1 ----------------
#pragma unroll
        for (int j = 0; j < 2; ++j) {
            b1[j][0] = *(const bf16x8*)&smem[bbase + 8192 + brow + (j << 10) + csel0];
            b1[j][1] = *(const bf16x8*)&smem[bbase + 8192 + brow + (j << 10) + csel1];
        }
        if (t + 2 < 32) STG_A(t + 2, 0);
        BAR();
        SCHED0();
        __builtin_amdgcn_s_setprio(1);
#pragma unroll
        for (int i = 0; i < 4; ++i)
#pragma unroll
            for (int j = 0; j < 2; ++j) {
                acc[i][2 + j] = mfma16(a[i][0], b1[j][0], acc[i][2 + j]);
                acc[i][2 + j] = mfma16(a[i][1], b1[j][1], acc[i][2 + j]);
            }
        __builtin_amdgcn_s_setprio(0);
        SCHED0();
        BAR();

        // ---------------- P3: A-mh1 ----------------
#pragma unroll
        for (int i = 0; i < 4; ++i) {
            a[i][0] = *(const bf16x8*)&smem[abase + 8192 + arow + (i << 10) + csel0];
            a[i][1] = *(const bf16x8*)&smem[abase + 8192 + arow + (i << 10) + csel1];
        }
        if (t + 2 < 32) STG_B(t + 2, 0);
        BAR();
        SCHED0();
        __builtin_amdgcn_s_setprio(1);
#pragma unroll
        for (int i = 0; i < 4; ++i)
#pragma unroll
            for (int j = 0; j < 2; ++j) {
                acc[4 + i][2 + j] = mfma16(a[i][0], b1[j][0], acc[4 + i][2 + j]);
                acc[4 + i][2 + j] = mfma16(a[i][1], b1[j][1], acc[4 + i][2 + j]);
            }
        __builtin_amdgcn_s_setprio(0);
        SCHED0();
        BAR();

        // ---------------- P4: register reuse ----------------
        if (t + 2 < 32) STG_A(t + 2, 1);
        BAR();
        SCHED0();
        __builtin_amdgcn_s_setprio(1);
#pragma unroll
        for (int i = 0; i < 4; ++i)
#pragma unroll
            for (int j = 0; j < 2; ++j) {
                acc[4 + i][j] = mfma16(a[i][0], b0[j][0], acc[4 + i][j]);
                acc[4 + i][j] = mfma16(a[i][1], b0[j][1], acc[4 + i][j]);
            }
        __builtin_amdgcn_s_setprio(0);
        SCHED0();
        if (t + 2 < 32) {
            WAITV(6);
        } else if (t + 1 < 32) {
            WAITV(0);
        }
        BAR();
    }

    // -------- epilogue: row = m0+wr*128+(mi>>2)*64+(mi&3)*16+lq*4+r,
    //                    col = n0+wc*64+(nj>>1)*32+(nj&1)*16+lr --------
    const int seg = n0 >> 11;
    const float* bias = (seg == 0) ? bq : (seg == 1) ? bk : bv;
    if (seg == 2) {
        // V: per-wave LDS transpose (2 passes of 64 rows), 16B stores
        bf16* lt = smem + w * 4608;  // 64 x 72 bf16 per wave
        const int cgb = (n0 & 2047) + wc * 64;
        const int h = cgb >> 7, d0 = cgb & 127;
        const int b = m0 >> 11;
        const int sb = (m0 & 2047) + wr * 128;
#pragma unroll
        for (int mh = 0; mh < 2; ++mh) {
#pragma unroll
            for (int mi = 0; mi < 4; ++mi)
#pragma unroll
                for (int nj = 0; nj < 4; ++nj) {
                    const int cl = ((nj >> 1) << 5) + ((nj & 1) << 4) + lr;
                    const float bv_ = bias[cgb + cl];
#pragma unroll
                    for (int r = 0; r < 4; ++r)
                        lt[cl * 72 + mi * 16 + lq * 4 + r] =
                            (bf16)(acc[mh * 4 + mi][nj][r] + bv_);
                }
            // within-wave LDS RAW ordered by lgkmcnt
#pragma unroll
            for (int p = 0; p < 8; ++p) {
                const int dl = p * 8 + (l >> 3);
                const int sc = l & 7;
                const bf16x8 v = *(const bf16x8*)&lt[dl * 72 + sc * 8];
                *(bf16x8*)&Vo[((size_t)((b << 4) | h) * HD + d0 + dl) * S_LEN +
                              sb + mh * 64 + sc * 8] = v;
            }
        }
    } else {
        bf16* outB = (seg == 0) ? Qo : Ko;
#pragma unroll
        for (int mi = 0; mi < 8; ++mi) {
            const int rg0 = m0 + wr * 128 + ((mi >> 2) << 6) + ((mi & 3) << 4) + (lq << 2);
#pragma unroll
            for (int nj = 0; nj < 4; ++nj) {
                const int cg2 = (n0 & 2047) + wc * 64 + ((nj >> 1) << 5) +
                                ((nj & 1) << 4) + lr;
                const float bv_ = bias[cg2];
                const int h = cg2 >> 7, d = cg2 & 127;
#pragma unroll
                for (int r = 0; r < 4; ++r) {
                    const int rg = rg0 + r;
                    const int b = rg >> 11, s = rg & 2047;
                    float v = acc[mi][nj][r] + bv_;
                    float p = __shfl_xor(v, 1);
                    const float sn = stab[(s << 7) | d];
                    const float cs = ctab[(s << 7) | d];
                    float o = (d & 1) ? (v * cs + p * sn) : (v * cs - p * sn);
                    if (seg == 0) o *= 0.08838834764831843f;  // 1/sqrt(128)
                    outB[((size_t)((b << 4) + h) * S_LEN + s) * HD + d] = (bf16)o;
                }
            }
        }
    }
}

// ---------------- output GEMM: out[4096,2048] fp32 = AO . Wt^T + bo ------
__global__ __launch_bounds__(256, 3)
void gemm_out(const bf16* __restrict__ A, const bf16* __restrict__ Bt,
              const float* __restrict__ bias, float* __restrict__ outF,
              int M, int N, int K) {
    __shared__ __align__(16) bf16 As[128 * 64];
    __shared__ __align__(16) bf16 Bs[128 * 64];
    const int t = threadIdx.x;
    const int w = t >> 6, l = t & 63;
    const int lr = l & 15, lq = l >> 4;
    const int m0 = blockIdx.y * 128, n0 = blockIdx.x * 128;
    const int wm = (w >> 1) * 64, wn = (w & 1) * 64;

    f32x4 acc[4][4];
    const f32x4 fz = {0.f, 0.f, 0.f, 0.f};
#pragma unroll
    for (int i = 0; i < 4; ++i)
#pragma unroll
        for (int j = 0; j < 4; ++j) acc[i][j] = fz;

    bf16x8 rA[4], rB[4];
#pragma unroll
    for (int c = 0; c < 4; ++c) {
        const int chunk = c * 256 + t;
        const int row = chunk >> 3, cc = chunk & 7;
        rA[c] = *(const bf16x8*)&A[(size_t)(m0 + row) * K + cc * 8];
        rB[c] = *(const bf16x8*)&Bt[(size_t)(n0 + row) * K + cc * 8];
    }

    for (int k0 = 0; k0 < K; k0 += 64) {
#pragma unroll
        for (int c = 0; c < 4; ++c) {
            const int chunk = c * 256 + t;
            const int row = chunk >> 3, cc = chunk & 7;
            const int d = (row * 8 + (cc ^ (row & 7))) * 8;
            *(bf16x8*)&As[d] = rA[c];
            *(bf16x8*)&Bs[d] = rB[c];
        }
        __syncthreads();
        if (k0 + 64 < K) {
#pragma unroll
            for (int c = 0; c < 4; ++c) {
                const int chunk = c * 256 + t;
                const int row = chunk >> 3, cc = chunk & 7;
                rA[c] = *(const bf16x8*)&A[(size_t)(m0 + row) * K + k0 + 64 + cc * 8];
                rB[c] = *(const bf16x8*)&Bt[(size_t)(n0 + row) * K + k0 + 64 + cc * 8];
            }
        }
#pragma unroll
        for (int s = 0; s < 2; ++s) {
            bf16x8 af[4], bfr[4];
#pragma unroll
            for (int i = 0; i < 4; ++i) {
                const int row = wm + i * 16 + lr;
                af[i] = *(const bf16x8*)&As[(row * 8 + ((s * 4 + lq) ^ (row & 7))) * 8];
            }
#pragma unroll
            for (int j = 0; j < 4; ++j) {
                const int row = wn + j * 16 + lr;
                bfr[j] = *(const bf16x8*)&Bs[(row * 8 + ((s * 4 + lq) ^ (row & 7))) * 8];
            }
#pragma unroll
            for (int i = 0; i < 4; ++i)
#pragma unroll
                for (int j = 0; j < 4; ++j)
                    acc[i][j] = mfma16(af[i], bfr[j], acc[i][j]);
        }
        __syncthreads();
    }
#pragma unroll
    for (int i = 0; i < 4; ++i) {
        const int rg0 = m0 + wm + i * 16 + lq * 4;
#pragma unroll
        for (int j = 0; j < 4; ++j) {
            const int cg = n0 + wn + j * 16 + lr;
            const float bv = bias[cg];
#pragma unroll
            for (int r = 0; r < 4; ++r)
                outF[(size_t)(rg0 + r) * N + cg] = acc[i][j][r] + bv;
        }
    }
}

// ---------------- flash attention (v5, unchanged) ----------------
// grid 512 (XCD-swizzled), 256 thr (4 waves x 32 q-rows), 64-key tiles,
// 32 iters. Register double-buffered staging; constant-max softmax; P
// aliased on Ks (wave-private rows). LDS 32KB -> 2 blocks/CU.
__global__ __launch_bounds__(256, 2)
void attn_fwd(const bf16* __restrict__ Q, const bf16* __restrict__ K,
              const bf16* __restrict__ Vt, bf16* __restrict__ AO) {
    __shared__ __align__(16) bf16 Ks[64 * 128];   // 16KB; P(128x64) alias
    __shared__ __align__(16) bf16 Vs[128 * 64];   // 16KB
    const int t = threadIdx.x;
    const int w = t >> 6, l = t & 63;
    const int lr = l & 15, lq = l >> 4;
    const int blk = blockIdx.x;
    const int qt = (blk >> 3) & 15;
    const int bh = ((blk & 7) << 2) | (blk >> 7);
    const int b = bh >> 4, h = bh & 15;

    const bf16* Qp = Q + (size_t)bh * S_LEN * HD;
    const bf16* Kp = K + (size_t)bh * S_LEN * HD;
    const bf16* Vp = Vt + (size_t)bh * HD * S_LEN;

    bf16x8 qf[2][4];
#pragma unroll
    for (int i = 0; i < 2; ++i)
#pragma unroll
        for (int s = 0; s < 4; ++s)
            qf[i][s] = *(const bf16x8*)&Qp[(size_t)(qt * 128 + w * 32 + i * 16 + lr) * HD +
                                           s * 32 + lq * 8];

    f32x4 O[2][8];
    const f32x4 fz = {0.f, 0.f, 0.f, 0.f};
#pragma unroll
    for (int i = 0; i < 2; ++i)
#pragma unroll
        for (int jd = 0; jd < 8; ++jd) O[i][jd] = fz;
    float lst[2][4] = {{0.f, 0.f, 0.f, 0.f}, {0.f, 0.f, 0.f, 0.f}};

    bf16x8 rK[4], rV[4];
#pragma unroll
    for (int c = 0; c < 4; ++c) {
        const int chunk = c * 256 + t;
        const int kr = chunk >> 4, kc = chunk & 15;
        const int vr = chunk >> 3, vc = chunk & 7;
        rK[c] = *(const bf16x8*)&Kp[(size_t)kr * HD + kc * 8];
        rV[c] = *(const bf16x8*)&Vp[(size_t)vr * S_LEN + vc * 8];
    }

    for (int kt = 0; kt < 32; ++kt) {
#pragma unroll
        for (int c = 0; c < 4; ++c) {
            const int chunk = c * 256 + t;
            const int kr = chunk >> 4, kc = chunk & 15;
            const int vr = chunk >> 3, vc = chunk & 7;
            *(bf16x8*)&Ks[(kr * 16 + (kc ^ (kr & 15))) * 8] = rK[c];
            *(bf16x8*)&Vs[(vr * 8 + (vc ^ (vr & 7))) * 8] = rV[c];
        }
        __syncthreads();  // tiles staged

        if (kt < 31) {
#pragma unroll
            for (int c = 0; c < 4; ++c) {
                const int chunk = c * 256 + t;
                const int kr = chunk >> 4, kc = chunk & 15;
                const int vr = chunk >> 3, vc = chunk & 7;
                rK[c] = *(const bf16x8*)&Kp[(size_t)((kt + 1) * 64 + kr) * HD + kc * 8];
                rV[c] = *(const bf16x8*)&Vp[(size_t)vr * S_LEN + (kt + 1) * 64 + vc * 8];
            }
        }

        f32x4 Sc[2][4];
#pragma unroll
        for (int i = 0; i < 2; ++i)
#pragma unroll
            for (int j = 0; j < 4; ++j) Sc[i][j] = fz;
#pragma unroll
        for (int s = 0; s < 4; ++s) {
            bf16x8 kf[4];
#pragma unroll
            for (int j = 0; j < 4; ++j) {
                const int krow = j * 16 + lr;
                kf[j] = *(const bf16x8*)&Ks[(krow * 16 + ((s * 4 + lq) ^ (krow & 15))) * 8];
            }
#pragma unroll
            for (int i = 0; i < 2; ++i)
#pragma unroll
                for (int j = 0; j < 4; ++j)
                    Sc[i][j] = mfma16(qf[i][s], kf[j], Sc[i][j]);
        }
        __syncthreads();  // Ks reads done before P overwrites

        bf16* Ps = Ks;
#pragma unroll
        for (int i = 0; i < 2; ++i)
#pragma unroll
            for (int j = 0; j < 4; ++j)
#pragma unroll
                for (int r = 0; r < 4; ++r) {
                    const float p = __expf(Sc[i][j][r]);
                    lst[i][r] += p;
                    const int prow = w * 32 + i * 16 + lq * 4 + r;
                    const int pch = (j * 2 + (lr >> 3)) ^ (prow & 7);
                    Ps[(prow * 8 + pch) * 8 + (lr & 7)] = (bf16)p;
                }
        // no barrier: within-wave LDS RAW ordered by lgkmcnt

#pragma unroll
        for (int s = 0; s < 2; ++s) {
            bf16x8 pf[2], vf[8];
#pragma unroll
            for (int i = 0; i < 2; ++i) {
                const int prow = w * 32 + i * 16 + lr;
                pf[i] = *(const bf16x8*)&Ps[(prow * 8 + ((s * 4 + lq) ^ (prow & 7))) * 8];
            }
#pragma unroll
            for (int jd = 0; jd < 8; ++jd) {
                const int vrow = jd * 16 + lr;
                vf[jd] = *(const bf16x8*)&Vs[(vrow * 8 + ((s * 4 + lq) ^ (vrow & 7))) * 8];
            }
#pragma unroll
            for (int i = 0; i < 2; ++i)
#pragma unroll
                for (int jd = 0; jd < 8; ++jd)
                    O[i][jd] = mfma16(pf[i], vf[jd], O[i][jd]);
        }
        __syncthreads();  // P/V reads done before next commit
    }

#pragma unroll
    for (int mask = 1; mask < 16; mask <<= 1)
#pragma unroll
        for (int i = 0; i < 2; ++i)
#pragma unroll
            for (int r = 0; r < 4; ++r) lst[i][r] += __shfl_xor(lst[i][r], mask);

#pragma unroll
    for (int i = 0; i < 2; ++i)
#pragma unroll
        for (int jd = 0; jd < 8; ++jd)
#pragma unroll
            for (int r = 0; r < 4; ++r) {
                const int srow = qt * 128 + w * 32 + i * 16 + lq * 4 + r;
                const float v = O[i][jd][r] / lst[i][r];
                AO[(size_t)(b * S_LEN + srow) * 2048 + h * HD + jd * 16 + lr] = (bf16)v;
            }
}

extern "C" void kernel_launch(void* const* d_in, const int* in_sizes, int n_in,
                              void* d_out, int out_size, void* d_ws, size_t ws_size,
                              hipStream_t stream) {
    const float* hs = (const float*)d_in[0];
    const float* Wq = (const float*)d_in[1];
    const float* bq = (const float*)d_in[2];
    const float* Wk = (const float*)d_in[3];
    const float* bk = (const float*)d_in[4];
    const float* Wv = (const float*)d_in[5];
    const float* bv = (const float*)d_in[6];
    const float* Wo = (const float*)d_in[7];
    const float* bo = (const float*)d_in[8];
    float* out = (float*)d_out;

    // ws: Xb/AO 16MB | Wt3 24MB | Q 16MB | K 16MB | Vt 16MB | sin 1MB | cos 1MB
    char* ws = (char*)d_ws;
    bf16* Xb = (bf16*)ws;
    bf16* Wt3 = (bf16*)(ws + (size_t)16777216);
    bf16* Qb = (bf16*)(ws + (size_t)41943040);
    bf16* Kb = (bf16*)(ws + (size_t)58720256);
    bf16* Vb = (bf16*)(ws + (size_t)75497472);
    float* stab = (float*)(ws + (size_t)92274688);
    float* ctab = (float*)(ws + (size_t)93323264);
    bf16* AO = Xb;  // X no longer needed after QKV projection

    const dim3 tg(64, 64);  // transpose grid

    rope_tables<<<2048, 128, 0, stream>>>(stab, ctab);
    cvt_f32_bf16<<<8192, 256, 0, stream>>>(hs, Xb, 8388608);
    transpose_cvt<<<tg, 256, 0, stream>>>(Wq, Wt3, 2048, 2048);
    transpose_cvt<<<tg, 256, 0, stream>>>(Wk, Wt3 + (size_t)2048 * 2048, 2048, 2048);
    transpose_cvt<<<tg, 256, 0, stream>>>(Wv, Wt3 + (size_t)2 * 2048 * 2048, 2048, 2048);
    gemm_qkv<<<dim3(24, 16), 512, 0, stream>>>(Xb, Wt3, bq, bk, bv, Qb, Kb, Vb,
                                               stab, ctab);
    attn_fwd<<<512, 256, 0, stream>>>(Qb, Kb, Vb, AO);
    transpose_cvt<<<tg, 256, 0, stream>>>(Wo, Wt3, 2048, 2048);
    gemm_out<<<dim3(16, 32), 256, 0, stream>>>(AO, Wt3, bo, out, 4096, 2048, 2048);
}

// Round 2
// 402.253 us; speedup vs baseline: 1.0096x; 1.0020x over previous
//
#include <hip/hip_runtime.h>
#include <math.h>

// Attention_10230612099272: B=2,S=2048,H=2048,nh=16,hd=128, fp32 in/out,
// bf16 MFMA internally.
// R8: gemm_qkv = 256x128 tile, 768 blocks (= exactly 3 full rounds of 256
// CUs -- kills R7's 1.5-round tail), 8 waves (4Mx2N, 64x64 each), BK=64,
// 96KB LDS 2-deep double buffer, 2 phases/K-tile x 16 MFMA, counted
// vmcnt(6) at both phase ends (never 0 in steady state), raw s_barrier,
// setprio around MFMA clusters, NO sched_barrier (m196: fine interleave is
// the lever). Stage units: A-r0 (rows 0-31 mod 64), B (128 rows), A-r1.
// Ledger (steady): enter Ph1 with 6 loads {A(t,r1),A(t+1,r0),B(t+1)};
// Ph1 +A(t+1,r1)->8, WAITV(6) drains A(t,r1); Ph2 +A(t+2,r0)+B(t+2)->10,
// WAITV(6) drains A(t+1,r0),B(t+1). gemm_out / attn unchanged.

typedef __bf16 bf16;
typedef __attribute__((ext_vector_type(8))) __bf16 bf16x8;
typedef __attribute__((ext_vector_type(4))) __bf16 bf16x4;
typedef __attribute__((ext_vector_type(4))) float f32x4;

#define S_LEN 2048
#define NHEAD 16
#define HD 128

__device__ __forceinline__ f32x4 mfma16(bf16x8 a, bf16x8 b, f32x4 c) {
    return __builtin_amdgcn_mfma_f32_16x16x32_bf16(a, b, c, 0, 0, 0);
}

__device__ __forceinline__ void gload16(const bf16* g, bf16* s) {
    __builtin_amdgcn_global_load_lds(
        (const __attribute__((address_space(1))) void*)g,
        (__attribute__((address_space(3))) void*)s, 16, 0, 0);
}

// raw barrier: no implicit vmcnt/lgkmcnt drain; empty asm = compiler fence
#define BAR()                                  \
    do {                                       \
        asm volatile("" ::: "memory");         \
        __builtin_amdgcn_s_barrier();          \
        asm volatile("" ::: "memory");         \
    } while (0)
#define WAITV(n) asm volatile("s_waitcnt vmcnt(" #n ")" ::: "memory")

// ---------------- fp32 -> bf16 elementwise ----------------
__global__ __launch_bounds__(256) void cvt_f32_bf16(const float* __restrict__ x,
                                                    bf16* __restrict__ y, int n) {
    int i = (blockIdx.x * 256 + threadIdx.x) * 4;
    if (i + 3 < n) {
        const float4 v = *(const float4*)(x + i);
        bf16x4 o;
        o[0] = (bf16)v.x; o[1] = (bf16)v.y; o[2] = (bf16)v.z; o[3] = (bf16)v.w;
        *(bf16x4*)(y + i) = o;
    }
}

// ---------------- RoPE sin/cos tables: [s][d], 2048x128 fp32 ----------
__global__ __launch_bounds__(128) void rope_tables(float* __restrict__ st,
                                                   float* __restrict__ ct) {
    const int s = blockIdx.x, d = threadIdx.x;
    const float invf = exp2f(-0.20762050593046013f * (float)(d >> 1));
    float sn, cs;
    sincosf((float)s * invf, &sn, &cs);
    st[(s << 7) | d] = sn;
    ct[(s << 7) | d] = cs;
}

// ---------------- W (k,n) fp32 -> Wt (n,k) bf16 ----------------
__global__ __launch_bounds__(256) void transpose_cvt(const float* __restrict__ W,
                                                     bf16* __restrict__ Wt,
                                                     int Kd, int Nd) {
    __shared__ float tile[32][33];
    const int tx = threadIdx.x & 31, ty = threadIdx.x >> 5;
    const int bn = blockIdx.x * 32, bk = blockIdx.y * 32;
#pragma unroll
    for (int r = 0; r < 32; r += 8)
        tile[ty + r][tx] = W[(size_t)(bk + ty + r) * Nd + bn + tx];
    __syncthreads();
#pragma unroll
    for (int r = 0; r < 32; r += 8)
        Wt[(size_t)(bn + ty + r) * Kd + bk + tx] = (bf16)tile[tx][ty + r];
}

// ------------- fused QKV GEMM: C[4096, 6144] = X . Wt3^T -------------
// 256x128 tile, BK=64, 8 waves (4Mx2N), 2 phases/K-tile:
//   Ph1: read A-r0 frags (4) + B frags (8); stage A(t+1,r1); BAR;
//        16 MFMA (i01 x j0..3); WAITV(6); BAR.
//   Ph2: read A-r1 frags (4); stage A(t+2,r0), B(t+2); BAR;
//        16 MFMA (i23 x j0..3); WAITV(6); BAR.
// A unit r0 = rows {r : r%64 < 32} (what i=0,1 reads), r1 = the rest.
// XOR chunk swizzle (cc ^= row&7) via inverse-swizzled GLOBAL source +
// linear LDS dest + swizzled read (rule #21: both-sides-or-neither).
// n-segment 0: Q (bias+RoPE, *1/sqrt(hd) -> [b,h,s,d]); 1: K (bias+RoPE);
// 2: V (bias -> Vt [b,h,d,s] via per-wave LDS transpose).
#define STG_A(kt, reg)                                                        \
    do {                                                                      \
        bf16* d_ = smem + (((((kt) & 1) << 1) + (reg)) << 13);                \
        const size_t ko_ = (size_t)((kt) << 6) + ((size_t)(reg) << 16);       \
        gload16(A + aoff0 + ko_, d_ + loff0);                                 \
        gload16(A + aoff1 + ko_, d_ + loff1);                                 \
    } while (0)
#define STG_B(kt)                                                             \
    do {                                                                      \
        bf16* d_ = smem + 32768 + (((kt) & 1) << 13);                         \
        const size_t ko_ = (size_t)((kt) << 6);                               \
        gload16(Bt + boff0 + ko_, d_ + loff0);                                \
        gload16(Bt + boff1 + ko_, d_ + loff1);                                \
    } while (0)

__global__ __launch_bounds__(512, 2)
void gemm_qkv(const bf16* __restrict__ A, const bf16* __restrict__ Bt,
              const float* __restrict__ bq, const float* __restrict__ bk,
              const float* __restrict__ bv, bf16* __restrict__ Qo,
              bf16* __restrict__ Ko, bf16* __restrict__ Vo,
              const float* __restrict__ stab, const float* __restrict__ ctab) {
    __shared__ __align__(16) bf16 smem[49152];  // 96KB: A[2][2][8192] | B[2][8192]
    const int tid = threadIdx.x;
    const int w = tid >> 6, l = tid & 63;
    const int lr = l & 15, lq = l >> 4;
    const int wr = w >> 1, wc = w & 1;  // 4M x 2N wave grid
    const int m0 = blockIdx.y * 256, n0 = blockIdx.x * 128;

    // per-thread staging offsets (chunk = c*512+tid; 16B each; src carries
    // the inverse XOR swizzle so linear LDS + swizzled read is consistent)
    size_t aoff0, aoff1, boff0, boff1;
    {
        const int ch0 = tid, ch1 = 512 + tid;
        const int rl0 = ch0 >> 3, rl1 = ch1 >> 3;
        const int cc0 = (ch0 & 7) ^ (rl0 & 7), cc1 = (ch1 & 7) ^ (rl1 & 7);
        aoff0 = (size_t)(m0 + ((rl0 >> 5) << 6) + (rl0 & 31)) * 2048 + (cc0 << 3);
        aoff1 = (size_t)(m0 + ((rl1 >> 5) << 6) + (rl1 & 31)) * 2048 + (cc1 << 3);
        boff0 = (size_t)(n0 + rl0) * 2048 + (cc0 << 3);
        boff1 = (size_t)(n0 + rl1) * 2048 + (cc1 << 3);
    }
    const int loff0 = tid << 3, loff1 = 4096 + (tid << 3);

    f32x4 acc[4][4];
    const f32x4 fz = {0.f, 0.f, 0.f, 0.f};
#pragma unroll
    for (int i = 0; i < 4; ++i)
#pragma unroll
        for (int j = 0; j < 4; ++j) acc[i][j] = fz;

    // prologue: tile0 (3 units) + 2 units of tile1; drain tile0's Ph1 deps
    STG_A(0, 0); STG_B(0); STG_A(0, 1); STG_A(1, 0); STG_B(1);
    WAITV(6);
    BAR();

    const int csel0 = ((0 * 4 + lq) ^ (lr & 7)) << 3;  // k-chunk byte sel, s=0
    const int csel1 = ((1 * 4 + lq) ^ (lr & 7)) << 3;  // s=1
    const int aoffL = (wr * 32 + lr) << 6;             // + (i&1)*1024
    const int boffL = (wc * 64 + lr) << 6;             // + j*1024

#pragma unroll 2
    for (int t = 0; t < 32; ++t) {
        const int buf = t & 1;
        const int abase = (buf << 1) << 13;
        const int bbase = 32768 + (buf << 13);
        bf16x8 a[2][2], b[4][2];

        // ---------------- Ph1: A-r0 (i=0,1) x all B ----------------
#pragma unroll
        for (int i = 0; i < 2; ++i) {
            a[i][0] = *(const bf16x8*)&smem[abase + aoffL + (i << 10) + csel0];
            a[i][1] = *(const bf16x8*)&smem[abase + aoffL + (i << 10) + csel1];
        }
#pragma unroll
        for (int j = 0; j < 4; ++j) {
            b[j][0] = *(const bf16x8*)&smem[bbase + boffL + (j << 10) + csel0];
            b[j][1] = *(const bf16x8*)&smem[bbase + boffL + (j << 10) + csel1];
        }
        if (t < 31) STG_A(t + 1, 1);
        BAR();
        __builtin_amdgcn_s_setprio(1);
#pragma unroll
        for (int i = 0; i < 2; ++i)
#pragma unroll
            for (int j = 0; j < 4; ++j) {
                acc[i][j] = mfma16(a[i][0], b[j][0], acc[i][j]);
                acc[i][j] = mfma16(a[i][1], b[j][1], acc[i][j]);
            }
        __builtin_amdgcn_s_setprio(0);
        if (t < 31) {
            WAITV(6);  // drains A(t,r1) -> Ph2 may read it
        } else {
            WAITV(0);
        }
        BAR();

        // ---------------- Ph2: A-r1 (i=2,3) x all B ----------------
#pragma unroll
        for (int i = 0; i < 2; ++i) {
            a[i][0] = *(const bf16x8*)&smem[abase + 8192 + aoffL + (i << 10) + csel0];
            a[i][1] = *(const bf16x8*)&smem[abase + 8192 + aoffL + (i << 10) + csel1];
        }
        if (t < 30) { STG_A(t + 2, 0); STG_B(t + 2); }
        BAR();
        __builtin_amdgcn_s_setprio(1);
#pragma unroll
        for (int i = 0; i < 2; ++i)
#pragma unroll
            for (int j = 0; j < 4; ++j) {
                acc[2 + i][j] = mfma16(a[i][0], b[j][0], acc[2 + i][j]);
                acc[2 + i][j] = mfma16(a[i][1], b[j][1], acc[2 + i][j]);
            }
        __builtin_amdgcn_s_setprio(0);
        if (t < 30) {
            WAITV(6);  // drains A(t+1,r0), B(t+1) -> next Ph1 may read
        } else if (t == 30) {
            WAITV(2);  // drains A(31,r0), B(31); A(31,r1) stays in flight
        }
        BAR();
    }

    // -------- epilogue: row = m0+wr*64+i*16+lq*4+r, col = n0+wc*64+j*16+lr
    const int seg = n0 >> 11;
    const float* bias = (seg == 0) ? bq : (seg == 1) ? bk : bv;
    if (seg == 2) {
        // V: per-wave LDS transpose (64 rows x 64 cols), 16B stores
        bf16* lt = smem + w * 4608;  // 64 x 72 bf16 per wave
        const int cgb = (n0 & 2047) + wc * 64;
        const int h = cgb >> 7, d0 = cgb & 127;
        const int b = m0 >> 11;
        const int sb = (m0 & 2047) + wr * 64;
#pragma unroll
        for (int i = 0; i < 4; ++i)
#pragma unroll
            for (int j = 0; j < 4; ++j) {
                const int cl = j * 16 + lr;
                const float bv_ = bias[cgb + cl];
#pragma unroll
                for (int r = 0; r < 4; ++r)
                    lt[cl * 72 + i * 16 + lq * 4 + r] = (bf16)(acc[i][j][r] + bv_);
            }
        // within-wave LDS RAW ordered by lgkmcnt
#pragma unroll
        for (int p = 0; p < 8; ++p) {
            const int dl = p * 8 + (l >> 3);
            const int sc = l & 7;
            const bf16x8 v = *(const bf16x8*)&lt[dl * 72 + sc * 8];
            *(bf16x8*)&Vo[((size_t)((b << 4) | h) * HD + d0 + dl) * S_LEN +
                          sb + sc * 8] = v;
        }
    } else {
        bf16* outB = (seg == 0) ? Qo : Ko;
#pragma unroll
        for (int i = 0; i < 4; ++i) {
            const int rg0 = m0 + wr * 64 + i * 16 + lq * 4;
#pragma unroll
            for (int j = 0; j < 4; ++j) {
                const int cg2 = (n0 & 2047) + wc * 64 + j * 16 + lr;
                const float bv_ = bias[cg2];
                const int h = cg2 >> 7, d = cg2 & 127;
#pragma unroll
                for (int r = 0; r < 4; ++r) {
                    const int rg = rg0 + r;
                    const int b = rg >> 11, s = rg & 2047;
                    float v = acc[i][j][r] + bv_;
                    float p = __shfl_xor(v, 1);
                    const float sn = stab[(s << 7) | d];
                    const float cs = ctab[(s << 7) | d];
                    float o = (d & 1) ? (v * cs + p * sn) : (v * cs - p * sn);
                    if (seg == 0) o *= 0.08838834764831843f;  // 1/sqrt(128)
                    outB[((size_t)((b << 4) + h) * S_LEN + s) * HD + d] = (bf16)o;
                }
            }
        }
    }
}

// ---------------- output GEMM: out[4096,2048] fp32 = AO . Wt^T + bo ------
__global__ __launch_bounds__(256, 3)
void gemm_out(const bf16* __restrict__ A, const bf16* __restrict__ Bt,
              const float* __restrict__ bias, float* __restrict__ outF,
              int M, int N, int K) {
    __shared__ __align__(16) bf16 As[128 * 64];
    __shared__ __align__(16) bf16 Bs[128 * 64];
    const int t = threadIdx.x;
    const int w = t >> 6, l = t & 63;
    const int lr = l & 15, lq = l >> 4;
    const int m0 = blockIdx.y * 128, n0 = blockIdx.x * 128;
    const int wm = (w >> 1) * 64, wn = (w & 1) * 64;

    f32x4 acc[4][4];
    const f32x4 fz = {0.f, 0.f, 0.f, 0.f};
#pragma unroll
    for (int i = 0; i < 4; ++i)
#pragma unroll
        for (int j = 0; j < 4; ++j) acc[i][j] = fz;

    bf16x8 rA[4], rB[4];
#pragma unroll
    for (int c = 0; c < 4; ++c) {
        const int chunk = c * 256 + t;
        const int row = chunk >> 3, cc = chunk & 7;
        rA[c] = *(const bf16x8*)&A[(size_t)(m0 + row) * K + cc * 8];
        rB[c] = *(const bf16x8*)&Bt[(size_t)(n0 + row) * K + cc * 8];
    }

    for (int k0 = 0; k0 < K; k0 += 64) {
#pragma unroll
        for (int c = 0; c < 4; ++c) {
            const int chunk = c * 256 + t;
            const int row = chunk >> 3, cc = chunk & 7;
            const int d = (row * 8 + (cc ^ (row & 7))) * 8;
            *(bf16x8*)&As[d] = rA[c];
            *(bf16x8*)&Bs[d] = rB[c];
        }
        __syncthreads();
        if (k0 + 64 < K) {
#pragma unroll
            for (int c = 0; c < 4; ++c) {
                const int chunk = c * 256 + t;
                const int row = chunk >> 3, cc = chunk & 7;
                rA[c] = *(const bf16x8*)&A[(size_t)(m0 + row) * K + k0 + 64 + cc * 8];
                rB[c] = *(const bf16x8*)&Bt[(size_t)(n0 + row) * K + k0 + 64 + cc * 8];
            }
        }
#pragma unroll
        for (int s = 0; s < 2; ++s) {
            bf16x8 af[4], bfr[4];
#pragma unroll
            for (int i = 0; i < 4; ++i) {
                const int row = wm + i * 16 + lr;
                af[i] = *(const bf16x8*)&As[(row * 8 + ((s * 4 + lq) ^ (row & 7))) * 8];
            }
#pragma unroll
            for (int j = 0; j < 4; ++j) {
                const int row = wn + j * 16 + lr;
                bfr[j] = *(const bf16x8*)&Bs[(row * 8 + ((s * 4 + lq) ^ (row & 7))) * 8];
            }
#pragma unroll
            for (int i = 0; i < 4; ++i)
#pragma unroll
                for (int j = 0; j < 4; ++j)
                    acc[i][j] = mfma16(af[i], bfr[j], acc[i][j]);
        }
        __syncthreads();
    }
#pragma unroll
    for (int i = 0; i < 4; ++i) {
        const int rg0 = m0 + wm + i * 16 + lq * 4;
#pragma unroll
        for (int j = 0; j < 4; ++j) {
            const int cg = n0 + wn + j * 16 + lr;
            const float bv = bias[cg];
#pragma unroll
            for (int r = 0; r < 4; ++r)
                outF[(size_t)(rg0 + r) * N + cg] = acc[i][j][r] + bv;
        }
    }
}

// ---------------- flash attention (v5, unchanged) ----------------
// grid 512 (XCD-swizzled), 256 thr (4 waves x 32 q-rows), 64-key tiles,
// 32 iters. Register double-buffered staging; constant-max softmax; P
// aliased on Ks (wave-private rows). LDS 32KB -> 2 blocks/CU.
__global__ __launch_bounds__(256, 2)
void attn_fwd(const bf16* __restrict__ Q, const bf16* __restrict__ K,
              const bf16* __restrict__ Vt, bf16* __restrict__ AO) {
    __shared__ __align__(16) bf16 Ks[64 * 128];   // 16KB; P(128x64) alias
    __shared__ __align__(16) bf16 Vs[128 * 64];   // 16KB
    const int t = threadIdx.x;
    const int w = t >> 6, l = t & 63;
    const int lr = l & 15, lq = l >> 4;
    const int blk = blockIdx.x;
    const int qt = (blk >> 3) & 15;
    const int bh = ((blk & 7) << 2) | (blk >> 7);
    const int b = bh >> 4, h = bh & 15;

    const bf16* Qp = Q + (size_t)bh * S_LEN * HD;
    const bf16* Kp = K + (size_t)bh * S_LEN * HD;
    const bf16* Vp = Vt + (size_t)bh * HD * S_LEN;

    bf16x8 qf[2][4];
#pragma unroll
    for (int i = 0; i < 2; ++i)
#pragma unroll
        for (int s = 0; s < 4; ++s)
            qf[i][s] = *(const bf16x8*)&Qp[(size_t)(qt * 128 + w * 32 + i * 16 + lr) * HD +
                                           s * 32 + lq * 8];

    f32x4 O[2][8];
    const f32x4 fz = {0.f, 0.f, 0.f, 0.f};
#pragma unroll
    for (int i = 0; i < 2; ++i)
#pragma unroll
        for (int jd = 0; jd < 8; ++jd) O[i][jd] = fz;
    float lst[2][4] = {{0.f, 0.f, 0.f, 0.f}, {0.f, 0.f, 0.f, 0.f}};

    bf16x8 rK[4], rV[4];
#pragma unroll
    for (int c = 0; c < 4; ++c) {
        const int chunk = c * 256 + t;
        const int kr = chunk >> 4, kc = chunk & 15;
        const int vr = chunk >> 3, vc = chunk & 7;
        rK[c] = *(const bf16x8*)&Kp[(size_t)kr * HD + kc * 8];
        rV[c] = *(const bf16x8*)&Vp[(size_t)vr * S_LEN + vc * 8];
    }

    for (int kt = 0; kt < 32; ++kt) {
#pragma unroll
        for (int c = 0; c < 4; ++c) {
            const int chunk = c * 256 + t;
            const int kr = chunk >> 4, kc = chunk & 15;
            const int vr = chunk >> 3, vc = chunk & 7;
            *(bf16x8*)&Ks[(kr * 16 + (kc ^ (kr & 15))) * 8] = rK[c];
            *(bf16x8*)&Vs[(vr * 8 + (vc ^ (vr & 7))) * 8] = rV[c];
        }
        __syncthreads();  // tiles staged

        if (kt < 31) {
#pragma unroll
            for (int c = 0; c < 4; ++c) {
                const int chunk = c * 256 + t;
                const int kr = chunk >> 4, kc = chunk & 15;
                const int vr = chunk >> 3, vc = chunk & 7;
                rK[c] = *(const bf16x8*)&Kp[(size_t)((kt + 1) * 64 + kr) * HD + kc * 8];
                rV[c] = *(const bf16x8*)&Vp[(size_t)vr * S_LEN + (kt + 1) * 64 + vc * 8];
            }
        }

        f32x4 Sc[2][4];
#pragma unroll
        for (int i = 0; i < 2; ++i)
#pragma unroll
            for (int j = 0; j < 4; ++j) Sc[i][j] = fz;
#pragma unroll
        for (int s = 0; s < 4; ++s) {
            bf16x8 kf[4];
#pragma unroll
            for (int j = 0; j < 4; ++j) {
                const int krow = j * 16 + lr;
                kf[j] = *(const bf16x8*)&Ks[(krow * 16 + ((s * 4 + lq) ^ (krow & 15))) * 8];
            }
#pragma unroll
            for (int i = 0; i < 2; ++i)
#pragma unroll
                for (int j = 0; j < 4; ++j)
                    Sc[i][j] = mfma16(qf[i][s], kf[j], Sc[i][j]);
        }
        __syncthreads();  // Ks reads done before P overwrites

        bf16* Ps = Ks;
#pragma unroll
        for (int i = 0; i < 2; ++i)
#pragma unroll
            for (int j = 0; j < 4; ++j)
#pragma unroll
                for (int r = 0; r < 4; ++r) {
                    const float p = __expf(Sc[i][j][r]);
                    lst[i][r] += p;
                    const int prow = w * 32 + i * 16 + lq * 4 + r;
                    const int pch = (j * 2 + (lr >> 3)) ^ (prow & 7);
                    Ps[(prow * 8 + pch) * 8 + (lr & 7)] = (bf16)p;
                }
        // no barrier: within-wave LDS RAW ordered by lgkmcnt

#pragma unroll
        for (int s = 0; s < 2; ++s) {
            bf16x8 pf[2], vf[8];
#pragma unroll
            for (int i = 0; i < 2; ++i) {
                const int prow = w * 32 + i * 16 + lr;
                pf[i] = *(const bf16x8*)&Ps[(prow * 8 + ((s * 4 + lq) ^ (prow & 7))) * 8];
            }
#pragma unroll
            for (int jd = 0; jd < 8; ++jd) {
                const int vrow = jd * 16 + lr;
                vf[jd] = *(const bf16x8*)&Vs[(vrow * 8 + ((s * 4 + lq) ^ (vrow & 7))) * 8];
            }
#pragma unroll
            for (int i = 0; i < 2; ++i)
#pragma unroll
                for (int jd = 0; jd < 8; ++jd)
                    O[i][jd] = mfma16(pf[i], vf[jd], O[i][jd]);
        }
        __syncthreads();  // P/V reads done before next commit
    }

#pragma unroll
    for (int mask = 1; mask < 16; mask <<= 1)
#pragma unroll
        for (int i = 0; i < 2; ++i)
#pragma unroll
            for (int r = 0; r < 4; ++r) lst[i][r] += __shfl_xor(lst[i][r], mask);

#pragma unroll
    for (int i = 0; i < 2; ++i)
#pragma unroll
        for (int jd = 0; jd < 8; ++jd)
#pragma unroll
            for (int r = 0; r < 4; ++r) {
                const int srow = qt * 128 + w * 32 + i * 16 + lq * 4 + r;
                const float v = O[i][jd][r] / lst[i][r];
                AO[(size_t)(b * S_LEN + srow) * 2048 + h * HD + jd * 16 + lr] = (bf16)v;
            }
}

extern "C" void kernel_launch(void* const* d_in, const int* in_sizes, int n_in,
                              void* d_out, int out_size, void* d_ws, size_t ws_size,
                              hipStream_t stream) {
    const float* hs = (const float*)d_in[0];
    const float* Wq = (const float*)d_in[1];
    const float* bq = (const float*)d_in[2];
    const float* Wk = (const float*)d_in[3];
    const float* bk = (const float*)d_in[4];
    const float* Wv = (const float*)d_in[5];
    const float* bv = (const float*)d_in[6];
    const float* Wo = (const float*)d_in[7];
    const float* bo = (const float*)d_in[8];
    float* out = (float*)d_out;

    // ws: Xb/AO 16MB | Wt3 24MB | Q 16MB | K 16MB | Vt 16MB | sin 1MB | cos 1MB
    char* ws = (char*)d_ws;
    bf16* Xb = (bf16*)ws;
    bf16* Wt3 = (bf16*)(ws + (size_t)16777216);
    bf16* Qb = (bf16*)(ws + (size_t)41943040);
    bf16* Kb = (bf16*)(ws + (size_t)58720256);
    bf16* Vb = (bf16*)(ws + (size_t)75497472);
    float* stab = (float*)(ws + (size_t)92274688);
    float* ctab = (float*)(ws + (size_t)93323264);
    bf16* AO = Xb;  // X no longer needed after QKV projection

    const dim3 tg(64, 64);  // transpose grid

    rope_tables<<<2048, 128, 0, stream>>>(stab, ctab);
    cvt_f32_bf16<<<8192, 256, 0, stream>>>(hs, Xb, 8388608);
    transpose_cvt<<<tg, 256, 0, stream>>>(Wq, Wt3, 2048, 2048);
    transpose_cvt<<<tg, 256, 0, stream>>>(Wk, Wt3 + (size_t)2048 * 2048, 2048, 2048);
    transpose_cvt<<<tg, 256, 0, stream>>>(Wv, Wt3 + (size_t)2 * 2048 * 2048, 2048, 2048);
    gemm_qkv<<<dim3(48, 16), 512, 0, stream>>>(Xb, Wt3, bq, bk, bv, Qb, Kb, Vb,
                                               stab, ctab);
    attn_fwd<<<512, 256, 0, stream>>>(Qb, Kb, Vb, AO);
    transpose_cvt<<<tg, 256, 0, stream>>>(Wo, Wt3, 2048, 2048);
    gemm_out<<<dim3(16, 32), 256, 0, stream>>>(AO, Wt3, bo, out, 4096, 2048, 2048);
}